// Round 4
// baseline (288.775 us; speedup 1.0000x reference)
//
#include <hip/hip_runtime.h>
#include <stdint.h>

// DVQ bottleneck: B=8, N=4096, D=1024, S=4, K=16, d=256, BETA=0.25
// Outputs (flat fp32 in d_out): z[8*4096*1024], ids_packed[32768] (as float),
// vq_total[1].
//
// R4: R3 structure (block = 4 waves = 64 tokens x 1 segment; wave = 64-float
// d-chunk; lane = token; codebook via wave-uniform scalar loads) BUT h is
// staged into LDS with global_load_lds width-16 (fully coalesced 1KB DMAs)
// instead of per-lane divergent global loads. Compute reads h from LDS.
// The cross-wave partial buffer aliases the 64KB tile after a barrier.

#define D_FULL 1024
#define SEG 4
#define DSEG 256
#define KC 16

#define GLOBAL_AS __attribute__((address_space(1)))
#define LDS_AS __attribute__((address_space(3)))

// Prep (64 blocks x 256): fp64 codebook copy, fp64 ||c||^2 per (s,k),
// zero ids_out + loss (d_out/d_ws poisoned 0xAA before every timed launch).
__global__ __launch_bounds__(256) void dvq_prep(const float* __restrict__ cb,
                                                double* __restrict__ cbd,
                                                double* __restrict__ c2d,
                                                float* __restrict__ ids_out,
                                                float* __restrict__ loss_out) {
    __shared__ double ws[4];
    const int b = blockIdx.x;    // 0..63 == (s,k) pair
    const int t = threadIdx.x;
    const int lane = t & 63;
    const int w = t >> 6;

    cbd[b * 256 + t] = (double)cb[b * 256 + t];

    ids_out[b * 512 + t] = 0.0f;
    ids_out[b * 512 + 256 + t] = 0.0f;
    if (b == 0 && t == 0) *loss_out = 0.0f;

    double v = (double)cb[b * 256 + t];
    double sq = v * v;
#pragma unroll
    for (int off = 32; off > 0; off >>= 1)
        sq += __shfl_down(sq, off, 64);
    if (lane == 0) ws[w] = sq;
    __syncthreads();
    if (t == 0) c2d[b] = ws[0] + ws[1] + ws[2] + ws[3];
}

__global__ __launch_bounds__(256, 2) void dvq_main(const float* __restrict__ h,
                                                   const float* __restrict__ cb,
                                                   const double* __restrict__ cbd,
                                                   const double* __restrict__ c2d,
                                                   float* __restrict__ z_out,
                                                   float* __restrict__ ids_out,
                                                   float* __restrict__ loss_out) {
    __shared__ __align__(16) float tile[64 * DSEG];  // 64 KB, aliased later
    __shared__ int ids_lds[64];

    const int i = threadIdx.x;
    const int lane = i & 63;                           // token within block
    const int w = i >> 6;                              // wave id == d-chunk
    const int ch = __builtin_amdgcn_readfirstlane(w);  // wave-uniform SGPR

    const int s = blockIdx.x & 3;                      // segment
    const long tok_base = (long)(blockIdx.x >> 2) * 64;

    // ---- Stage: 16 coalesced 1KB DMAs per wave (wave w stages tokens
    // w*16..w*16+15). LDS dest = uniform base + lane*16 (row-major tile). ----
    {
        const float* gbase = h + (tok_base + ch * 16) * D_FULL + (long)s * DSEG;
        float* lbase = tile + (ch * 16) * DSEG;
#pragma unroll
        for (int r = 0; r < 16; ++r) {
            const float* gp = gbase + (long)r * D_FULL + lane * 4;
            float* lp = lbase + r * DSEG;
            __builtin_amdgcn_global_load_lds((GLOBAL_AS void*)gp,
                                             (LDS_AS void*)lp, 16, 0, 0);
        }
    }
    __syncthreads();  // drains vmcnt (DMA) + makes tile visible

    // ---- Compute: fp64 partial dots over this wave's 64-float chunk.
    // h from LDS (per-lane row), codebook via wave-uniform scalar loads. ----
    const float4* zp = (const float4*)(tile + lane * DSEG + ch * 64);
    const double* cbs = cbd + s * (KC * DSEG) + ch * 64;  // wave-uniform

    double dot[KC];
#pragma unroll
    for (int k = 0; k < KC; ++k) dot[k] = 0.0;
    double ze2 = 0.0;

#pragma unroll 4
    for (int j = 0; j < 16; ++j) {
        float4 z4 = zp[j];
        double z0 = (double)z4.x, z1 = (double)z4.y;
        double z2 = (double)z4.z, z3 = (double)z4.w;
        ze2 = fma(z0, z0, ze2);
        ze2 = fma(z1, z1, ze2);
        ze2 = fma(z2, z2, ze2);
        ze2 = fma(z3, z3, ze2);
#pragma unroll
        for (int k = 0; k < KC; ++k) {
            const double* ck = cbs + k * DSEG + j * 4;  // scalar loads
            double a = dot[k];
            a = fma(z0, ck[0], a);
            a = fma(z1, ck[1], a);
            a = fma(z2, ck[2], a);
            a = fma(z3, ck[3], a);
            dot[k] = a;
        }
    }

    // ---- Cross-wave reduction: partials alias the tile (reads are done) ----
    __syncthreads();  // everyone finished reading tile
    double* part = (double*)tile;  // [3][64][17] doubles = 25.5 KB
    if (w != 0) {
        double* p = part + ((w - 1) * 64 + lane) * (KC + 1);
#pragma unroll
        for (int k = 0; k < KC; ++k) p[k] = dot[k];
        p[KC] = ze2;
    }
    __syncthreads();

    if (w == 0) {
#pragma unroll
        for (int c = 0; c < 3; ++c) {
            const double* p = part + (c * 64 + lane) * (KC + 1);
#pragma unroll
            for (int k = 0; k < KC; ++k) dot[k] += p[k];
            ze2 += p[KC];
        }

        // argmin; strict < keeps lowest k (jnp.argmin first-index tie-break)
        const double* c2s = c2d + s * KC;
        double best = c2s[0] - 2.0 * dot[0];
        int bk = 0;
#pragma unroll
        for (int k = 1; k < KC; ++k) {
            double sc = c2s[k] - 2.0 * dot[k];
            if (sc < best) { best = sc; bk = k; }
        }
        ids_lds[lane] = bk;

        // ids_packed contribution: bk * 16^s, exact in fp32 (<= 61440)
        atomicAdd(&ids_out[tok_base + lane], (float)(bk << (4 * s)));

        // loss: min dist = ||ze||^2 + (||c||^2 - 2 ze.c), reduce 64 tokens
        double mind = ze2 + best;
#pragma unroll
        for (int off = 32; off > 0; off >>= 1)
            mind += __shfl_down(mind, off, 64);
        if (lane == 0)
            atomicAdd(loss_out, (float)(mind * (1.25 / 8388608.0)));
    }
    __syncthreads();  // ids_lds visible to all waves

    // ---- Phase 2: z write, 16 rows per wave, coalesced 1KB per row-seg ----
    const float4* cbf4 = (const float4*)cb;
#pragma unroll 4
    for (int r0 = 0; r0 < 16; ++r0) {
        int r = ch * 16 + r0;
        int k = ids_lds[r];  // wave-uniform
        float4 v = cbf4[(s * KC + k) * (DSEG / 4) + lane];
        ((float4*)(z_out + (tok_base + r) * D_FULL + (long)s * DSEG))[lane] = v;
    }
}

extern "C" void kernel_launch(void* const* d_in, const int* in_sizes, int n_in,
                              void* d_out, int out_size, void* d_ws, size_t ws_size,
                              hipStream_t stream) {
    const float* h  = (const float*)d_in[0];
    const float* cb = (const float*)d_in[1];

    const int n_h = in_sizes[0];          // 33554432
    const int tokens = n_h / D_FULL;      // 32768

    float* z_out    = (float*)d_out;
    float* ids_out  = z_out + (size_t)n_h;
    float* loss_out = ids_out + tokens;

    double* cbd = (double*)d_ws;                  // 16384 doubles
    double* c2d = cbd + SEG * KC * DSEG;          // 64 doubles

    dvq_prep<<<64, 256, 0, stream>>>(cb, cbd, c2d, ids_out, loss_out);
    dvq_main<<<(tokens / 64) * SEG, 256, 0, stream>>>(h, cb, cbd, c2d, z_out,
                                                      ids_out, loss_out);
}

// Round 5
// 261.066 us; speedup vs baseline: 1.1061x; 1.1061x over previous
//
#include <hip/hip_runtime.h>

// DVQ bottleneck: B=8, N=4096, D=1024, S=4, K=16, d=256, BETA=0.25
// Outputs (flat fp32 in d_out): z[8*4096*1024], ids_packed[32768] (as float),
// vq_total[1].
//
// R5: R3 structure (block = 4 waves = 64 tokens x 1 segment; wave = 64-float
// d-chunk; lane = token; direct per-lane float4 h loads) BUT the fp64
// codebook slice for this block's segment (16k x 256d = 32 KB) is staged
// into LDS once per block. Inner-loop codebook reads are wave-uniform
// ds_read broadcasts (conflict-free) instead of s_loads -- R1/R3/R4 all
// plateaued at ~105-128us on scalar-K$ thrash (8 KB of s_loads per
// wave-task missing to L2). Partial-dot buffer aliases the codebook LDS
// after compute ends.

#define D_FULL 1024
#define SEG 4
#define DSEG 256
#define KC 16

// Prep (64 blocks x 256): fp64 codebook copy, fp64 ||c||^2 per (s,k),
// zero ids_out + loss (d_out/d_ws poisoned 0xAA before every timed launch).
__global__ __launch_bounds__(256) void dvq_prep(const float* __restrict__ cb,
                                                double* __restrict__ cbd,
                                                double* __restrict__ c2d,
                                                float* __restrict__ ids_out,
                                                float* __restrict__ loss_out) {
    __shared__ double ws[4];
    const int b = blockIdx.x;    // 0..63 == (s,k) pair
    const int t = threadIdx.x;
    const int lane = t & 63;
    const int w = t >> 6;

    cbd[b * 256 + t] = (double)cb[b * 256 + t];

    ids_out[b * 512 + t] = 0.0f;
    ids_out[b * 512 + 256 + t] = 0.0f;
    if (b == 0 && t == 0) *loss_out = 0.0f;

    double v = (double)cb[b * 256 + t];
    double sq = v * v;
#pragma unroll
    for (int off = 32; off > 0; off >>= 1)
        sq += __shfl_down(sq, off, 64);
    if (lane == 0) ws[w] = sq;
    __syncthreads();
    if (t == 0) c2d[b] = ws[0] + ws[1] + ws[2] + ws[3];
}

__global__ __launch_bounds__(256) void dvq_main(const float* __restrict__ h,
                                                const float* __restrict__ cb,
                                                const double* __restrict__ cbd,
                                                const double* __restrict__ c2d,
                                                float* __restrict__ z_out,
                                                float* __restrict__ ids_out,
                                                float* __restrict__ loss_out) {
    // 32 KB codebook slice; after compute it is aliased by the cross-wave
    // partial buffer [3][64][17] doubles = 26.1 KB.
    __shared__ __align__(16) double cbl[KC * DSEG];
    __shared__ int ids_lds[64];

    const int i = threadIdx.x;
    const int lane = i & 63;                           // token within block
    const int w = i >> 6;                              // wave id == d-chunk
    const int ch = __builtin_amdgcn_readfirstlane(w);  // wave-uniform SGPR

    const int s = blockIdx.x & 3;                      // segment
    const long tok_base = (long)(blockIdx.x >> 2) * 64;
    const long tok = tok_base + lane;

    // ---- Stage fp64 codebook slice to LDS (coalesced, L2-resident src) ----
    {
        const double* src = cbd + s * (KC * DSEG);
#pragma unroll
        for (int jj = 0; jj < 16; ++jj)
            cbl[jj * 256 + i] = src[jj * 256 + i];
    }
    __syncthreads();

    // ---- Phase 1: fp64 partial dots over this wave's 64-float chunk.
    // h per-lane global float4; codebook via wave-uniform LDS broadcast. ----
    const float4* zp = (const float4*)(h + tok * D_FULL + (long)s * DSEG + ch * 64);
    const double* cbs = cbl + ch * 64;  // LDS, wave-uniform

    double dot[KC];
#pragma unroll
    for (int k = 0; k < KC; ++k) dot[k] = 0.0;
    double ze2 = 0.0;

#pragma unroll 4
    for (int j = 0; j < 16; ++j) {
        float4 z4 = zp[j];
        double z0 = (double)z4.x, z1 = (double)z4.y;
        double z2 = (double)z4.z, z3 = (double)z4.w;
        ze2 = fma(z0, z0, ze2);
        ze2 = fma(z1, z1, ze2);
        ze2 = fma(z2, z2, ze2);
        ze2 = fma(z3, z3, ze2);
#pragma unroll
        for (int k = 0; k < KC; ++k) {
            const double* ck = cbs + k * DSEG + j * 4;  // broadcast ds_read
            double a = dot[k];
            a = fma(z0, ck[0], a);
            a = fma(z1, ck[1], a);
            a = fma(z2, ck[2], a);
            a = fma(z3, ck[3], a);
            dot[k] = a;
        }
    }

    // ---- Cross-wave reduction: partials alias cbl (codebook reads done) ----
    __syncthreads();  // all waves finished reading cbl
    double* part = (double*)cbl;  // [3][64][17]
    if (w != 0) {
        double* p = part + ((w - 1) * 64 + lane) * (KC + 1);
#pragma unroll
        for (int k = 0; k < KC; ++k) p[k] = dot[k];
        p[KC] = ze2;
    }
    __syncthreads();

    if (w == 0) {
#pragma unroll
        for (int c = 0; c < 3; ++c) {
            const double* p = part + (c * 64 + lane) * (KC + 1);
#pragma unroll
            for (int k = 0; k < KC; ++k) dot[k] += p[k];
            ze2 += p[KC];
        }

        // argmin; strict < keeps lowest k (jnp.argmin first-index tie-break)
        const double* c2s = c2d + s * KC;  // 128 B, scalar loads, K$-friendly
        double best = c2s[0] - 2.0 * dot[0];
        int bk = 0;
#pragma unroll
        for (int k = 1; k < KC; ++k) {
            double sc = c2s[k] - 2.0 * dot[k];
            if (sc < best) { best = sc; bk = k; }
        }
        ids_lds[lane] = bk;

        // ids_packed contribution: bk * 16^s, exact in fp32 (<= 61440)
        atomicAdd(&ids_out[tok], (float)(bk << (4 * s)));

        // loss: min dist = ||ze||^2 + (||c||^2 - 2 ze.c), reduce 64 tokens
        double mind = ze2 + best;
#pragma unroll
        for (int off = 32; off > 0; off >>= 1)
            mind += __shfl_down(mind, off, 64);
        if (lane == 0)
            atomicAdd(loss_out, (float)(mind * (1.25 / 8388608.0)));
    }
    __syncthreads();  // ids_lds visible to all waves

    // ---- Phase 2: z write, 16 rows per wave, coalesced 1KB per row-seg ----
    const float4* cbf4 = (const float4*)cb;
#pragma unroll 4
    for (int r0 = 0; r0 < 16; ++r0) {
        int r = ch * 16 + r0;
        int k = ids_lds[r];  // wave-uniform
        float4 v = cbf4[(s * KC + k) * (DSEG / 4) + lane];
        ((float4*)(z_out + (tok_base + r) * D_FULL + (long)s * DSEG))[lane] = v;
    }
}

extern "C" void kernel_launch(void* const* d_in, const int* in_sizes, int n_in,
                              void* d_out, int out_size, void* d_ws, size_t ws_size,
                              hipStream_t stream) {
    const float* h  = (const float*)d_in[0];
    const float* cb = (const float*)d_in[1];

    const int n_h = in_sizes[0];          // 33554432
    const int tokens = n_h / D_FULL;      // 32768

    float* z_out    = (float*)d_out;
    float* ids_out  = z_out + (size_t)n_h;
    float* loss_out = ids_out + tokens;

    double* cbd = (double*)d_ws;                  // 16384 doubles
    double* c2d = cbd + SEG * KC * DSEG;          // 64 doubles

    dvq_prep<<<64, 256, 0, stream>>>(cb, cbd, c2d, ids_out, loss_out);
    dvq_main<<<(tokens / 64) * SEG, 256, 0, stream>>>(h, cb, cbd, c2d, z_out,
                                                      ids_out, loss_out);
}